// Round 2
// baseline (11293.493 us; speedup 1.0000x reference)
//
#include <hip/hip_runtime.h>
#include <stdint.h>

#define B_   128
#define T_   64
#define V_   1024
#define TS_  64
#define H_   512
#define K_   (V_ + TS_)   // 1088

// ---------------------------------------------------------------------------
// Fully fused time-aware GRU scan.
//
// 256 workgroups x 1 wave (trivially co-resident on 256 CUs). WG g owns
// h[j0], h[j1] (j0 = 2g). Register-resident weights per WG:
//   - 6 rows of W_hh  (r/z/n gates for j0,j1):  48 VGPRs
//   - 6 rows of W_ih  (same gate rows):        102 VGPRs
// Per active step (t < lens[b], masked steps are identity and skipped):
//   1. load x = [visit_emb[b,t,:] | interval*W_time+b_time] (coalesced),
//      compute the 6 x-side dot products  -- INDEPENDENT of h, so this work
//      overlaps the inter-WG h round-trip and stays off the critical path.
//   2. poll the double-buffered h exchange: each 64-bit word is
//      (version<<32)|float_bits written/read with relaxed agent-scope
//      atomics -- data+flag fused, one coherence round-trip, no fences.
//   3. h-side dots, single 8-value wave butterfly, gates, h update,
//      tagged store of the new h words.
// Double-buffer safety: a WG can write version v+2 into a slot only after
// observing ALL words of v+1, which requires every WG to have finished
// reading v (value dependency through the dot product).
// d_ws poison 0xAAAAAAAA never collides with version tags (ver <= ~4100).
// Workspace use: 8 KiB (h_buf only) -- no xg materialization.
// ---------------------------------------------------------------------------

__device__ __forceinline__ float sigmoidf_(float x) {
    return 1.0f / (1.0f + __expf(-x));
}
__device__ __forceinline__ float tanhf_(float x) {
    x = fminf(fmaxf(x, -15.0f), 15.0f);
    const float e = __expf(2.0f * x);
    return (e - 1.0f) / (e + 1.0f);
}

__global__ __launch_bounds__(64, 1) void gru_fused(
    const float* __restrict__ visit_emb, const float* __restrict__ intervals,
    const float* __restrict__ W_time, const float* __restrict__ b_time,
    const float* __restrict__ W_ih, const float* __restrict__ W_hh,
    const float* __restrict__ b_ih, const float* __restrict__ b_hh,
    const int* __restrict__ lens, uint64_t* h_buf /* [2][H_] */,
    float* __restrict__ out)
{
    const int wg   = blockIdx.x;      // 0..255
    const int lane = threadIdx.x;     // 0..63
    const int j0   = wg * 2;
    const int j1   = j0 + 1;

    // ---- register-resident W_hh rows (k = lane + 64u) -------------------
    float wr0[8], wr1[8], wz0[8], wz1[8], wn0[8], wn1[8];
    #pragma unroll
    for (int u = 0; u < 8; ++u) {
        const int k = lane + 64 * u;
        wr0[u] = W_hh[(size_t)j0 * H_ + k];
        wr1[u] = W_hh[(size_t)j1 * H_ + k];
        wz0[u] = W_hh[(size_t)(H_ + j0) * H_ + k];
        wz1[u] = W_hh[(size_t)(H_ + j1) * H_ + k];
        wn0[u] = W_hh[(size_t)(2 * H_ + j0) * H_ + k];
        wn1[u] = W_hh[(size_t)(2 * H_ + j1) * H_ + k];
    }
    // ---- register-resident W_ih rows: u<16 visit part, u==16 time part --
    float ir0[17], ir1[17], iz0[17], iz1[17], in0[17], in1[17];
    #pragma unroll
    for (int u = 0; u < 16; ++u) {
        const int k = lane + 64 * u;
        ir0[u] = W_ih[(size_t)j0 * K_ + k];
        ir1[u] = W_ih[(size_t)j1 * K_ + k];
        iz0[u] = W_ih[(size_t)(H_ + j0) * K_ + k];
        iz1[u] = W_ih[(size_t)(H_ + j1) * K_ + k];
        in0[u] = W_ih[(size_t)(2 * H_ + j0) * K_ + k];
        in1[u] = W_ih[(size_t)(2 * H_ + j1) * K_ + k];
    }
    ir0[16] = W_ih[(size_t)j0 * K_ + V_ + lane];
    ir1[16] = W_ih[(size_t)j1 * K_ + V_ + lane];
    iz0[16] = W_ih[(size_t)(H_ + j0) * K_ + V_ + lane];
    iz1[16] = W_ih[(size_t)(H_ + j1) * K_ + V_ + lane];
    in0[16] = W_ih[(size_t)(2 * H_ + j0) * K_ + V_ + lane];
    in1[16] = W_ih[(size_t)(2 * H_ + j1) * K_ + V_ + lane];

    const float wt = W_time[lane];    // time-emb weight/bias for ts = lane
    const float bt = b_time[lane];

    const float bir0 = b_ih[j0],          bir1 = b_ih[j1];
    const float biz0 = b_ih[H_ + j0],     biz1 = b_ih[H_ + j1];
    const float bin0 = b_ih[2 * H_ + j0], bin1 = b_ih[2 * H_ + j1];
    const float bhr0 = b_hh[j0],          bhr1 = b_hh[j1];
    const float bhz0 = b_hh[H_ + j0],     bhz1 = b_hh[H_ + j1];
    const float bhn0 = b_hh[2 * H_ + j0], bhn1 = b_hh[2 * H_ + j1];

    float hj0 = 0.0f, hj1 = 0.0f;
    uint32_t ver = 1;  // version 1 == initial zero state

    if (lane == 0)
        __hip_atomic_store(&h_buf[(ver & 1) * H_ + j0], (uint64_t)ver << 32,
                           __ATOMIC_RELAXED, __HIP_MEMORY_SCOPE_AGENT);
    if (lane == 1)
        __hip_atomic_store(&h_buf[(ver & 1) * H_ + j1], (uint64_t)ver << 32,
                           __ATOMIC_RELAXED, __HIP_MEMORY_SCOPE_AGENT);

    for (int b = 0; b < B_; ++b) {
        const int L = lens[b];
        for (int t = 0; t < L; ++t) {
            // ---- x-side: independent of h, overlaps the h round-trip ----
            const float iv = intervals[b * T_ + t];
            const float* vrow = visit_emb + (size_t)(b * T_ + t) * V_;
            float xv[16];
            #pragma unroll
            for (int u = 0; u < 16; ++u) xv[u] = vrow[lane + 64 * u];
            const float xt = fmaf(iv, wt, bt);

            float ar0 = ir0[16] * xt, ar1 = ir1[16] * xt;
            float az0 = iz0[16] * xt, az1 = iz1[16] * xt;
            float xn0 = in0[16] * xt, xn1 = in1[16] * xt;
            #pragma unroll
            for (int u = 0; u < 16; ++u) {
                ar0 = fmaf(ir0[u], xv[u], ar0);
                ar1 = fmaf(ir1[u], xv[u], ar1);
                az0 = fmaf(iz0[u], xv[u], az0);
                az1 = fmaf(iz1[u], xv[u], az1);
                xn0 = fmaf(in0[u], xv[u], xn0);
                xn1 = fmaf(in1[u], xv[u], xn1);
            }

            // ---- poll current h version (k = lane + 64u) ----------------
            const uint64_t* src = h_buf + (ver & 1) * H_;
            uint64_t w[8];
            bool ok;
            do {
                ok = true;
                #pragma unroll
                for (int u = 0; u < 8; ++u) {
                    w[u] = __hip_atomic_load(&src[lane + 64 * u],
                                             __ATOMIC_RELAXED, __HIP_MEMORY_SCOPE_AGENT);
                    ok = ok && ((uint32_t)(w[u] >> 32) == ver);
                }
            } while (!__all(ok));

            float h[8];
            #pragma unroll
            for (int u = 0; u < 8; ++u) h[u] = __uint_as_float((uint32_t)w[u]);

            // ---- h-side dots; r/z merged with x-side, n kept split ------
            float hn0 = 0.0f, hn1 = 0.0f;
            #pragma unroll
            for (int u = 0; u < 8; ++u) {
                ar0 = fmaf(wr0[u], h[u], ar0);
                ar1 = fmaf(wr1[u], h[u], ar1);
                az0 = fmaf(wz0[u], h[u], az0);
                az1 = fmaf(wz1[u], h[u], az1);
                hn0 = fmaf(wn0[u], h[u], hn0);
                hn1 = fmaf(wn1[u], h[u], hn1);
            }
            // ---- single 8-value wave butterfly --------------------------
            #pragma unroll
            for (int m = 1; m < 64; m <<= 1) {
                ar0 += __shfl_xor(ar0, m, 64);
                ar1 += __shfl_xor(ar1, m, 64);
                az0 += __shfl_xor(az0, m, 64);
                az1 += __shfl_xor(az1, m, 64);
                xn0 += __shfl_xor(xn0, m, 64);
                xn1 += __shfl_xor(xn1, m, 64);
                hn0 += __shfl_xor(hn0, m, 64);
                hn1 += __shfl_xor(hn1, m, 64);
            }

            const float r0 = sigmoidf_(ar0 + bir0 + bhr0);
            const float r1 = sigmoidf_(ar1 + bir1 + bhr1);
            const float z0 = sigmoidf_(az0 + biz0 + bhz0);
            const float z1 = sigmoidf_(az1 + biz1 + bhz1);
            const float n0 = tanhf_(xn0 + bin0 + r0 * (hn0 + bhn0));
            const float n1 = tanhf_(xn1 + bin1 + r1 * (hn1 + bhn1));
            hj0 = (1.0f - z0) * n0 + z0 * hj0;
            hj1 = (1.0f - z1) * n1 + z1 * hj1;

            // ---- publish h' with embedded version tag -------------------
            ++ver;
            uint64_t* dst = h_buf + (ver & 1) * H_;
            if (lane == 0)
                __hip_atomic_store(&dst[j0],
                    ((uint64_t)ver << 32) | (uint64_t)__float_as_uint(hj0),
                    __ATOMIC_RELAXED, __HIP_MEMORY_SCOPE_AGENT);
            if (lane == 1)
                __hip_atomic_store(&dst[j1],
                    ((uint64_t)ver << 32) | (uint64_t)__float_as_uint(hj1),
                    __ATOMIC_RELAXED, __HIP_MEMORY_SCOPE_AGENT);
        }
        // out[b] = h after sample b's (possibly empty) segment
        if (lane == 0) out[b * H_ + j0] = hj0;
        if (lane == 1) out[b * H_ + j1] = hj1;
    }
}

// ---------------------------------------------------------------------------
extern "C" void kernel_launch(void* const* d_in, const int* in_sizes, int n_in,
                              void* d_out, int out_size, void* d_ws, size_t ws_size,
                              hipStream_t stream)
{
    const float* visit_emb = (const float*)d_in[0];
    const float* intervals = (const float*)d_in[1];
    const float* W_time    = (const float*)d_in[2];
    const float* b_time    = (const float*)d_in[3];
    const float* W_ih      = (const float*)d_in[4];
    const float* W_hh      = (const float*)d_in[5];
    const float* b_ih      = (const float*)d_in[6];
    const float* b_hh      = (const float*)d_in[7];
    const int*   lens      = (const int*)d_in[8];
    float*       out       = (float*)d_out;

    // workspace: only the h exchange buffer (2 x 512 x u64 = 8 KiB)
    uint64_t* h_buf = (uint64_t*)d_ws;

    gru_fused<<<256, 64, 0, stream>>>(visit_emb, intervals, W_time, b_time,
                                      W_ih, W_hh, b_ih, b_hh, lens, h_buf, out);
}